// Round 10
// baseline (542.481 us; speedup 1.0000x reference)
//
#include <hip/hip_runtime.h>
#include <hip/hip_fp16.h>
#include <hip/hip_bf16.h>
#include <stdint.h>

// ---------------------------------------------------------------------------
// ResidualVQ: x (64,512,256) f32, codebooks (6,1024,512) f32
// outputs: quantized_out (64,512,256), indices (64,256,6) as f32,
//          mean_loss, mean_perplexity   -> d_out flat f32, 8486914 elems
//
// R14 -> R15: GEMM traffic redesign. R14 profile: gemm = 55us cold
// (MfmaUtil 11%, HBM 3%, occ 21%) -- and R9's "22us" was the warm 2nd
// copy (probe confound). All prior gemm shapes read A (rbf, written by
// refine on OTHER XCDs) with 4x tn-redundancy => ~67MB cross-XCD L3
// traffic, structure-independent ~35us in-pipeline. New gemm: grid 256
// (1 block/CU), block = 64 rows x ALL 1024 cols, 8 waves x 128 cols.
// A read EXACTLY once (64KB/block); B slice (1MB) read-only -> per-XCD
// L2-hot. LDS lA 4KB + lB 64KB single buffer, plain 2-barrier loop
// (scheduling proven not the lever in R6-R8). XOR chunk swizzle pair
// (gch source / cq read) preserved; involution re-verified for new row
// bases (all ==0 mod 8). Fragment/epilogue mapping identical; each block
// writes all 16 cand groups for its 64 rows.
// refine = R11's block-per-row verbatim (best measured, 35.7us).
// ---------------------------------------------------------------------------

#define NTROWS 16384
#define DDIM   512
#define CCODES 1024
#define QSTAGE 6

// ws layout (bytes)
#define OFF_R      ((size_t)0)           // fp32 residual  NT*D*4   = 33554432
#define OFF_RBF    ((size_t)33554432)    // bf16 residual  NT*D*2   = 16777216
#define OFF_CBBF   ((size_t)50331648)    // bf16 codebooks 6*1024*512*2 = 6291456
#define OFF_CAND   ((size_t)56623104)    // u32 cand       NT*32*4   = 2097152
#define OFF_CBSQ   ((size_t)58720256)    // f32 |c|^2, 6*1024*4
#define OFF_HIST   ((size_t)58744832)    // u32 hist, 6*1024*4
#define OFF_LOSS   ((size_t)58769408)    // f32 loss bins, 6*256*4
#define WS_END     ((size_t)58775552)

#define OUT_IDX_OFF  ((size_t)8388608)
#define OUT_SCAL_OFF ((size_t)8486912)

typedef __attribute__((ext_vector_type(8))) short short8;
typedef __attribute__((ext_vector_type(8))) unsigned short ushort8v;
typedef __attribute__((ext_vector_type(4))) float f32x4;

__device__ __forceinline__ unsigned short f2bf(float f) {
    uint32_t u = __float_as_uint(f);
    uint32_t r = (u + 0x7fffu + ((u >> 16) & 1u)) >> 16;   // RNE
    return (unsigned short)r;
}
__device__ __forceinline__ uint32_t fkey(float f) {        // order-preserving f32->u32
    uint32_t u = __float_as_uint(f);
    return u ^ ((uint32_t)((int32_t)u >> 31) | 0x80000000u);
}
__device__ __forceinline__ float funkey(uint32_t k) {
    uint32_t u = (k & 0x80000000u) ? (k ^ 0x80000000u) : ~k;
    return __uint_as_float(u);
}
__device__ __forceinline__ uint32_t umin32(uint32_t a, uint32_t b) { return a < b ? a : b; }
__device__ __forceinline__ uint32_t umax32(uint32_t a, uint32_t b) { return a > b ? a : b; }
__device__ __forceinline__ unsigned long long umin64(unsigned long long a,
                                                     unsigned long long b) {
    return a < b ? a : b;
}
__device__ __forceinline__ float wave_sum(float v) {
    for (int m = 32; m; m >>= 1) v += __shfl_xor(v, m, 64);
    return v;
}
__device__ __forceinline__ uint32_t wave_min_u32(uint32_t v) {
    for (int m = 32; m; m >>= 1) v = umin32(v, (uint32_t)__shfl_xor((int)v, m, 64));
    return v;
}
__device__ __forceinline__ void async_load16(const void* g, void* l) {
    __builtin_amdgcn_global_load_lds(
        (__attribute__((address_space(1))) void*)(void*)g,
        (__attribute__((address_space(3))) void*)l, 16, 0, 0);
}

// --------------------------------------------------------------------------
// prep: blocks [0,1536): bf16 codebooks + |c|^2 (+ zero hist/loss in blk 0)
//       blocks [1536,9728): transpose x (N,D,T) -> r (NT,D) fp32+bf16
// grid 9728 x 256
// --------------------------------------------------------------------------
__global__ __launch_bounds__(256) void prep_kernel(
    const float* __restrict__ x, const float* __restrict__ cb,
    float* __restrict__ r, unsigned short* __restrict__ rbf,
    unsigned short* __restrict__ cbbf, float* __restrict__ cbsq,
    unsigned int* __restrict__ hist, float* __restrict__ loss_bins)
{
    __shared__ float tile[32][33];
    if (blockIdx.x < 1536) {
        const int wave = threadIdx.x >> 6, lane = threadIdx.x & 63;
        const int row = blockIdx.x * 4 + wave;            // 0..6143
        const float* p = cb + (size_t)row * DDIM;
        unsigned short* pb = cbbf + (size_t)row * DDIM;
        float s = 0.f;
#pragma unroll
        for (int t = 0; t < 8; ++t) {
            float v = p[lane + 64 * t];
            pb[lane + 64 * t] = f2bf(v);
            s += v * v;
        }
        s = wave_sum(s);
        if (lane == 0) cbsq[row] = s;
        if (blockIdx.x == 0) {
            for (int i = threadIdx.x; i < QSTAGE * CCODES; i += 256) hist[i] = 0u;
            for (int i = threadIdx.x; i < QSTAGE * 256; i += 256) loss_bins[i] = 0.f;
        }
    } else {
        const int bidx = blockIdx.x - 1536;               // 0..8191
        const int d0 = (bidx & 15) * 32;
        const int t0 = ((bidx >> 4) & 7) * 32;
        const int n  = bidx >> 7;
        const int tx = threadIdx.x & 31, ty = threadIdx.x >> 5;
        const float* xp = x + (size_t)n * (DDIM * 256);
#pragma unroll
        for (int s = 0; s < 4; ++s) {
            int dd = ty + s * 8;
            tile[dd][tx] = xp[(size_t)(d0 + dd) * 256 + t0 + tx];
        }
        __syncthreads();
#pragma unroll
        for (int s = 0; s < 4; ++s) {
            int tt = ty + s * 8;
            float v = tile[tx][tt];
            size_t off = (size_t)(n * 256 + t0 + tt) * DDIM + d0 + tx;
            r[off] = v;
            rbf[off] = f2bf(v);
        }
    }
}

// --------------------------------------------------------------------------
// GEMM: dist'[row][col] = cbsq[col] - 2 * dot(r_row, c_col), bf16 MFMA.
// grid 256 x 512: block b = rows [b*64, b*64+64), ALL 1024 cols.
// wave w covers cols [w*128, w*128+128). A read once; B L2-hot.
// LDS: lA[64][32] (4KB) + lB[1024][32] (64KB), single buffer, 2 barriers
// per K-step. XOR chunk swizzle preserved (slot c of row r holds global
// chunk c^((r>>1)&3); read cq = (quad^((l15>>1)&3))*8 recovers chunk=quad
// for any frag base == 0 mod 8).
// --------------------------------------------------------------------------
#define GBK 32
__global__ __launch_bounds__(512, 2) void gemm_dist_kernel(
    const unsigned short* __restrict__ Abf,   // NT x 512 bf16
    const unsigned short* __restrict__ Bbf,   // 1024 x 512 bf16 (stage slice)
    const float* __restrict__ cbsq,           // 1024 (stage slice)
    uint32_t* __restrict__ cand)              // NT x 16 x {k1,k2}
{
    __shared__ __align__(16) unsigned short lA[64 * GBK];     //  4 KiB
    __shared__ __align__(16) unsigned short lB[1024 * GBK];   // 64 KiB
    const int tid = threadIdx.x;
    const int wave = tid >> 6, lane = tid & 63;
    const int quad = lane >> 4, l15 = lane & 15;
    const int b = blockIdx.x;

    f32x4 acc[4][8];
#pragma unroll
    for (int i = 0; i < 4; ++i)
#pragma unroll
        for (int j = 0; j < 8; ++j) acc[i][j] = (f32x4){0.f, 0.f, 0.f, 0.f};

    // staging: source chunk gch = (lane&3)^((lane>>3)&3); LDS slot lane&3.
    const int gch = (lane & 3) ^ ((lane >> 3) & 3);
    // A: waves 0-3 stage rows [wave*16, wave*16+16) of the block's 64-row slab
    const unsigned short* gA =
        Abf + ((size_t)b * 64 + wave * 16 + (lane >> 2)) * DDIM + gch * 8;
    unsigned short* sA = &lA[(wave * 16) * GBK] + lane * 8;
    // B: wave w stages rows [w*128 + t*16, +16), t = 0..7
    const unsigned short* gB0 =
        Bbf + ((size_t)wave * 128 + (lane >> 2)) * DDIM + gch * 8;
    unsigned short* sB = &lB[(wave * 128) * GBK] + lane * 8;

    const int cq = (quad ^ ((l15 >> 1) & 3)) * 8;   // swizzled read chunk

    for (int kt = 0; kt < 16; ++kt) {
        const size_t ko = (size_t)kt * GBK;
        if (wave < 4) async_load16(gA + ko, sA);
#pragma unroll
        for (int t = 0; t < 8; ++t)
            async_load16(gB0 + (size_t)t * 16 * DDIM + ko, sB + t * 16 * GBK);
        __syncthreads();   // drains vmcnt(0) before reads

        short8 af[4], bfr[8];
#pragma unroll
        for (int i = 0; i < 4; ++i)
            af[i] = *(const short8*)&lA[(i * 16 + l15) * GBK + cq];
#pragma unroll
        for (int j = 0; j < 8; ++j)
            bfr[j] = *(const short8*)&lB[(wave * 128 + j * 16 + l15) * GBK + cq];

        __builtin_amdgcn_s_setprio(1);
#pragma unroll
        for (int i = 0; i < 4; ++i)
#pragma unroll
            for (int j = 0; j < 8; ++j)
                acc[i][j] = __builtin_amdgcn_mfma_f32_16x16x32_bf16(
                    af[i], bfr[j], acc[i][j], 0, 0, 0);
        __builtin_amdgcn_s_setprio(0);
        __syncthreads();   // before next stage overwrites
    }

    // epilogue: row = b*64 + i*16 + quad*4 + reg; col = wave*128 + j*16 + l15
    // (same verified mapping as R6-R14). Group g = wave*2 + jh.
    const int rowq = b * 64 + quad * 4;
    const int colb = wave * 128 + l15;
    float cbs[8];
#pragma unroll
    for (int j = 0; j < 8; ++j) cbs[j] = cbsq[colb + j * 16];
#pragma unroll
    for (int i = 0; i < 4; ++i) {
#pragma unroll
        for (int reg = 0; reg < 4; ++reg) {
            const int row = rowq + i * 16 + reg;
#pragma unroll
            for (int jh = 0; jh < 2; ++jh) {
                uint32_t k[4];
#pragma unroll
                for (int jj = 0; jj < 4; ++jj) {
                    const int j = jh * 4 + jj;
                    float dv = cbs[j] - 2.0f * acc[i][j][reg];
                    k[jj] = (fkey(dv) & ~1023u) | (uint32_t)(colb + j * 16);
                }
                // top-2 of 4 (tournament)
                uint32_t m01 = umin32(k[0], k[1]), M01 = umax32(k[0], k[1]);
                uint32_t m23 = umin32(k[2], k[3]), M23 = umax32(k[2], k[3]);
                uint32_t k1 = umin32(m01, m23);
                uint32_t k2 = umin32(umax32(m01, m23), umin32(M01, M23));
                // merge across the 16 lanes of this quad (xor stays in-quad)
#pragma unroll
                for (int m = 1; m < 16; m <<= 1) {
                    uint32_t o1 = (uint32_t)__shfl_xor((int)k1, m, 64);
                    uint32_t o2 = (uint32_t)__shfl_xor((int)k2, m, 64);
                    uint32_t n1 = umin32(k1, o1);
                    uint32_t n2 = umin32(umax32(k1, o1), umin32(k2, o2));
                    k1 = n1; k2 = n2;
                }
                if (l15 == 0)
                    *(uint2*)&cand[((size_t)row * 16 + wave * 2 + jh) * 2] =
                        make_uint2(k1, k2);
            }
        }
    }
}

// --------------------------------------------------------------------------
// refine+update (block-per-row, R11 verbatim — best measured): grid 16384x256.
// 4 waves/row: each wave loads the full row + own sumx; wave w handles
// masked candidates at positions == w (mod 4); per-wave best packed
// (fkey(de)<<32)|cc -> LDS min of 4 (exact argmin + tie-break);
// residual update coalesced across all 256 threads (float2/thread).
// --------------------------------------------------------------------------
#define MARGIN 8.0f
__global__ __launch_bounds__(256) void refine_kernel(
    float* __restrict__ r, unsigned short* __restrict__ rbf,
    const float* __restrict__ cbq, const float* __restrict__ cbsqq,
    const uint32_t* __restrict__ cand,
    float* __restrict__ out_idx, unsigned int* __restrict__ histq,
    float* __restrict__ loss_bins, int q, int write_bf)
{
    __shared__ unsigned long long sbest[4];
    const int tid = threadIdx.x;
    const int wave = tid >> 6, lane = tid & 63;
    const int nt = blockIdx.x;

    uint32_t key = 0xFFFFFFFFu;
    if (lane < 32) key = cand[(size_t)nt * 32 + lane];

    const float4* r4 = (const float4*)(r + (size_t)nt * DDIM);
    float4 ra = r4[lane * 2], rb = r4[lane * 2 + 1];
    float s = ra.x * ra.x + ra.y * ra.y + ra.z * ra.z + ra.w * ra.w
            + rb.x * rb.x + rb.y * rb.y + rb.z * rb.z + rb.w * rb.w;
    const float sumx = wave_sum(s);

    const uint32_t kmin = wave_min_u32(key);
    const float thr = funkey(kmin & ~1023u) + MARGIN;
    unsigned long long mask = __ballot(lane < 32 && funkey(key & ~1023u) <= thr);

    float best = 1e30f;
    int bestc = CCODES;
    int cnt = 0;
    while (mask) {
        const int src = __ffsll(mask) - 1;
        mask &= mask - 1;
        if ((cnt++ & 3) != wave) continue;   // round-robin split across 4 waves
        const int cc = __shfl((int)(key & 1023u), src, 64);
        const float4* crow = (const float4*)(cbq + (size_t)cc * DDIM);
        float4 ca = crow[lane * 2], cb2 = crow[lane * 2 + 1];
        float dot = ra.x * ca.x + ra.y * ca.y + ra.z * ca.z + ra.w * ca.w
                  + rb.x * cb2.x + rb.y * cb2.y + rb.z * cb2.z + rb.w * cb2.w;
        dot = wave_sum(dot);
        const float de = (sumx - 2.0f * dot) + cbsqq[cc];
        if (de < best || (de == best && cc < bestc)) { best = de; bestc = cc; }
    }
    if (lane == 0)
        sbest[wave] = ((unsigned long long)fkey(best) << 32) | (unsigned)bestc;
    __syncthreads();
    const unsigned long long bmin =
        umin64(umin64(sbest[0], sbest[1]), umin64(sbest[2], sbest[3]));
    bestc = (int)(bmin & 0xFFFFFFFFu);
    best  = funkey((uint32_t)(bmin >> 32));

    // coalesced residual update: 256 threads x float2 = 512 floats
    const float2* rr  = (const float2*)(r + (size_t)nt * DDIM);
    const float2* cbr = (const float2*)(cbq + (size_t)bestc * DDIM);
    float2 rv = rr[tid], cv = cbr[tid];
    float2 nv = make_float2(rv.x - cv.x, rv.y - cv.y);
    ((float2*)(r + (size_t)nt * DDIM))[tid] = nv;
    if (write_bf) {
        uint32_t pk = (uint32_t)f2bf(nv.x) | ((uint32_t)f2bf(nv.y) << 16);
        ((uint32_t*)(rbf + (size_t)nt * DDIM))[tid] = pk;
    }

    if (tid == 0) {
        out_idx[(size_t)nt * QSTAGE + q] = (float)bestc;
        atomicAdd(&histq[bestc], 1u);
        atomicAdd(&loss_bins[q * 256 + (blockIdx.x & 255)], best);
    }
}

// --------------------------------------------------------------------------
// final: blocks [0,8192): out = x - r_final transposed back to (N,D,T);
//        block 8192: mean commit loss + mean perplexity
// grid 8193 x 256
// --------------------------------------------------------------------------
__global__ __launch_bounds__(256) void final_kernel(
    const float* __restrict__ x, const float* __restrict__ r,
    float* __restrict__ out,
    const unsigned int* __restrict__ hist, const float* __restrict__ loss_bins,
    float* __restrict__ out2)
{
    __shared__ float tile[32][33];    // [t'][d']
    __shared__ float red[4];
    __shared__ float perp_acc;
    const int tid = threadIdx.x, wave = tid >> 6, lane = tid & 63;

    if (blockIdx.x < 8192) {
        const int bidx = blockIdx.x;
        const int d0 = (bidx & 15) * 32;
        const int t0 = ((bidx >> 4) & 7) * 32;
        const int n  = bidx >> 7;
        const int tx = tid & 31, ty = tid >> 5;
#pragma unroll
        for (int s = 0; s < 4; ++s) {
            int tt = ty + s * 8;
            tile[tt][tx] = r[(size_t)(n * 256 + t0 + tt) * DDIM + d0 + tx];
        }
        __syncthreads();
        const float* xp = x + (size_t)n * (DDIM * 256);
        float* op = out + (size_t)n * (DDIM * 256);
#pragma unroll
        for (int s = 0; s < 4; ++s) {
            int dd = ty + s * 8;
            size_t off = (size_t)(d0 + dd) * 256 + t0 + tx;
            op[off] = xp[off] - tile[tx][dd];
        }
        return;
    }

    // scalars block
    if (tid == 0) perp_acc = 0.f;
    __syncthreads();
    for (int q = 0; q < QSTAGE; ++q) {
        float s = 0.f;
        for (int c = tid; c < CCODES; c += 256) {
            float p = (float)hist[q * CCODES + c] * (1.0f / (float)NTROWS);
            s += p * logf(p + 1e-10f);
        }
        s = wave_sum(s);
        if (lane == 0) red[wave] = s;
        __syncthreads();
        if (tid == 0) {
            float tot = red[0] + red[1] + red[2] + red[3];
            perp_acc += expf(-tot);
        }
        __syncthreads();
    }
    float ls = 0.f;
    for (int i = tid; i < QSTAGE * 256; i += 256) ls += loss_bins[i];
    ls = wave_sum(ls);
    if (lane == 0) red[wave] = ls;
    __syncthreads();
    if (tid == 0) {
        float lsum = red[0] + red[1] + red[2] + red[3];
        out2[0] = (lsum / (float)QSTAGE) / ((float)NTROWS * (float)DDIM);
        out2[1] = perp_acc / (float)QSTAGE;
    }
}

// --------------------------------------------------------------------------
extern "C" void kernel_launch(void* const* d_in, const int* in_sizes, int n_in,
                              void* d_out, int out_size, void* d_ws, size_t ws_size,
                              hipStream_t stream)
{
    const float* x  = (const float*)d_in[0];
    const float* cb = (const float*)d_in[1];
    float* out = (float*)d_out;
    char* ws = (char*)d_ws;

    float*          r      = (float*)(ws + OFF_R);
    unsigned short* rbf    = (unsigned short*)(ws + OFF_RBF);
    unsigned short* cbbf   = (unsigned short*)(ws + OFF_CBBF);
    uint32_t*       cand   = (uint32_t*)(ws + OFF_CAND);
    float*          cbsq   = (float*)(ws + OFF_CBSQ);
    unsigned int*   hist   = (unsigned int*)(ws + OFF_HIST);
    float*          lbins  = (float*)(ws + OFF_LOSS);

    prep_kernel<<<9728, 256, 0, stream>>>(x, cb, r, rbf, cbbf, cbsq, hist, lbins);

    for (int q = 0; q < QSTAGE; ++q) {
        const size_t cboff = (size_t)q * CCODES * DDIM;
        gemm_dist_kernel<<<256, 512, 0, stream>>>(
            rbf, cbbf + cboff, cbsq + q * CCODES, cand);
        refine_kernel<<<NTROWS, 256, 0, stream>>>(
            r, rbf, cb + cboff, cbsq + q * CCODES, cand,
            out + OUT_IDX_OFF, hist + q * CCODES, lbins,
            q, (q < QSTAGE - 1) ? 1 : 0);
    }

    final_kernel<<<8193, 256, 0, stream>>>(x, r, out, hist, lbins,
                                           out + OUT_SCAL_OFF);
}

// Round 11
// 426.036 us; speedup vs baseline: 1.2733x; 1.2733x over previous
//
#include <hip/hip_runtime.h>
#include <hip/hip_fp16.h>
#include <hip/hip_bf16.h>
#include <stdint.h>

// ---------------------------------------------------------------------------
// ResidualVQ: x (64,512,256) f32, codebooks (6,1024,512) f32
// outputs: quantized_out (64,512,256), indices (64,256,6) as f32,
//          mean_loss, mean_perplexity   -> d_out flat f32, 8486914 elems
//
// R15 -> R16: FULL FUSION. Evidence (R6-R15): every kernel latency-bound
// reading the previous kernel's freshly-written data (cross-XCD dirty L2).
// Key fact: after prep the 6-stage recursion is ROW-INDEPENDENT -> one
// kernel, 256 blocks x 512 thr, each block owns 64 rows IN REGISTERS
// (rA/rB 64 VGPR/thr) across all 6 stages. Residual never round-trips;
// bf16 A regenerated per stage into LDS (f2bf of live regs == old rbf,
// bit-identical); B streamed from read-only cbbf (L2-hot); candidates via
// 8KB LDS scratch (replaces global cand). GEMM = R15's verified 64-row
// fragment/swizzle pair + R6's db + counted-vmcnt K-loop; refine = R14's
// verified 4-row-interleave on register rows. Math bit-identical
// throughout. 3 dispatches total (prep / fused / final).
// ---------------------------------------------------------------------------

#define NTROWS 16384
#define DDIM   512
#define CCODES 1024
#define QSTAGE 6

// ws layout (bytes)
#define OFF_R      ((size_t)0)           // fp32 residual  NT*D*4   = 33554432
#define OFF_CBBF   ((size_t)50331648)    // bf16 codebooks 6*1024*512*2
#define OFF_CBSQ   ((size_t)58720256)    // f32 |c|^2, 6*1024*4
#define OFF_HIST   ((size_t)58744832)    // u32 hist, 6*1024*4
#define OFF_LOSS   ((size_t)58769408)    // f32 loss bins, 6*256*4

#define OUT_IDX_OFF  ((size_t)8388608)
#define OUT_SCAL_OFF ((size_t)8486912)

typedef __attribute__((ext_vector_type(8))) short short8;
typedef __attribute__((ext_vector_type(8))) unsigned short ushort8v;
typedef __attribute__((ext_vector_type(4))) float f32x4;

__device__ __forceinline__ unsigned short f2bf(float f) {
    uint32_t u = __float_as_uint(f);
    uint32_t r = (u + 0x7fffu + ((u >> 16) & 1u)) >> 16;   // RNE
    return (unsigned short)r;
}
__device__ __forceinline__ uint32_t fkey(float f) {        // order-preserving f32->u32
    uint32_t u = __float_as_uint(f);
    return u ^ ((uint32_t)((int32_t)u >> 31) | 0x80000000u);
}
__device__ __forceinline__ float funkey(uint32_t k) {
    uint32_t u = (k & 0x80000000u) ? (k ^ 0x80000000u) : ~k;
    return __uint_as_float(u);
}
__device__ __forceinline__ uint32_t umin32(uint32_t a, uint32_t b) { return a < b ? a : b; }
__device__ __forceinline__ uint32_t umax32(uint32_t a, uint32_t b) { return a > b ? a : b; }
__device__ __forceinline__ float wave_sum(float v) {
    for (int m = 32; m; m >>= 1) v += __shfl_xor(v, m, 64);
    return v;
}
__device__ __forceinline__ void async_load16(const void* g, void* l) {
    __builtin_amdgcn_global_load_lds(
        (__attribute__((address_space(1))) void*)(void*)g,
        (__attribute__((address_space(3))) void*)l, 16, 0, 0);
}

// --------------------------------------------------------------------------
// prep: blocks [0,1536): bf16 codebooks + |c|^2 (+ zero hist/loss in blk 0)
//       blocks [1536,9728): transpose x (N,D,T) -> r (NT,D) fp32
// grid 9728 x 256   (rbf dropped — fused kernel regenerates bf16 itself)
// --------------------------------------------------------------------------
__global__ __launch_bounds__(256) void prep_kernel(
    const float* __restrict__ x, const float* __restrict__ cb,
    float* __restrict__ r,
    unsigned short* __restrict__ cbbf, float* __restrict__ cbsq,
    unsigned int* __restrict__ hist, float* __restrict__ loss_bins)
{
    __shared__ float tile[32][33];
    if (blockIdx.x < 1536) {
        const int wave = threadIdx.x >> 6, lane = threadIdx.x & 63;
        const int row = blockIdx.x * 4 + wave;            // 0..6143
        const float* p = cb + (size_t)row * DDIM;
        unsigned short* pb = cbbf + (size_t)row * DDIM;
        float s = 0.f;
#pragma unroll
        for (int t = 0; t < 8; ++t) {
            float v = p[lane + 64 * t];
            pb[lane + 64 * t] = f2bf(v);
            s += v * v;
        }
        s = wave_sum(s);
        if (lane == 0) cbsq[row] = s;
        if (blockIdx.x == 0) {
            for (int i = threadIdx.x; i < QSTAGE * CCODES; i += 256) hist[i] = 0u;
            for (int i = threadIdx.x; i < QSTAGE * 256; i += 256) loss_bins[i] = 0.f;
        }
    } else {
        const int bidx = blockIdx.x - 1536;               // 0..8191
        const int d0 = (bidx & 15) * 32;
        const int t0 = ((bidx >> 4) & 7) * 32;
        const int n  = bidx >> 7;
        const int tx = threadIdx.x & 31, ty = threadIdx.x >> 5;
        const float* xp = x + (size_t)n * (DDIM * 256);
#pragma unroll
        for (int s = 0; s < 4; ++s) {
            int dd = ty + s * 8;
            tile[dd][tx] = xp[(size_t)(d0 + dd) * 256 + t0 + tx];
        }
        __syncthreads();
#pragma unroll
        for (int s = 0; s < 4; ++s) {
            int tt = ty + s * 8;
            r[(size_t)(n * 256 + t0 + tt) * DDIM + d0 + tx] = tile[tx][tt];
        }
    }
}

// --------------------------------------------------------------------------
// FUSED: grid 256 x 512. Block b owns rows [b*64, b*64+64) in registers
// (wave w rows w*8..+8; lane l holds elems [l*8, l*8+8) as rA/rB float4).
// Per stage q: build lA bf16 (f2bf of regs, R15 swizzle layout) -> GEMM
// 64x1024 in two 512-col chunks (db lB, counted vmcnt, R15 frag mapping)
// -> top-2 per 64-col group into cand_lds -> refine (R14 4-row interleave,
// LDS cand + register rows + read-only fp32 cb) -> update regs. After 6
// stages: write residual back to r (for final_kernel).
// --------------------------------------------------------------------------
#define MARGIN 8.0f
__global__ __launch_bounds__(512, 2) void fused_vq_kernel(
    float* __restrict__ r,                     // NT x 512 fp32 (in/out)
    const unsigned short* __restrict__ cbbf,   // 6*1024*512 bf16
    const float* __restrict__ cb,              // 6*1024*512 f32
    const float* __restrict__ cbsq,            // 6*1024
    float* __restrict__ out_idx, unsigned int* __restrict__ hist,
    float* __restrict__ loss_bins)
{
    __shared__ __align__(16) unsigned short lA[16][64][32];   // 64 KiB [kt][row][slot]
    __shared__ __align__(16) unsigned short lB[2][512][32];   // 64 KiB
    __shared__ uint32_t cand_lds[64][32];                     //  8 KiB

    const int tid = threadIdx.x;
    const int wave = tid >> 6, lane = tid & 63;
    const int quad = lane >> 4, l15 = lane & 15;
    const int nt_base = blockIdx.x * 64;

    // ---- load own 8 rows into registers ----
    float4 rA[8], rB[8];
#pragma unroll
    for (int rr = 0; rr < 8; ++rr) {
        const float* rp = r + (size_t)(nt_base + wave * 8 + rr) * DDIM + lane * 8;
        rA[rr] = *(const float4*)rp;
        rB[rr] = *(const float4*)(rp + 4);
    }

    const int gch = (lane & 3) ^ ((lane >> 3) & 3);   // staging source chunk
    const int cq  = (quad ^ ((l15 >> 1) & 3)) * 8;    // swizzled read chunk

    for (int q = 0; q < QSTAGE; ++q) {
        const unsigned short* cbbf_q = cbbf + (size_t)q * CCODES * DDIM;
        const float* cb_q   = cb   + (size_t)q * CCODES * DDIM;
        const float* cbsq_q = cbsq + q * CCODES;

        // ---- build lA: row rlocal = wave*8+rr, lane l writes its 8 bf16
        // (elems l*8..+8) to [ktile l>>2][row][slot (l&3)^((row>>1)&3)] ----
#pragma unroll
        for (int rr = 0; rr < 8; ++rr) {
            const int rl = wave * 8 + rr;
            ushort8v pk;
            pk[0] = f2bf(rA[rr].x); pk[1] = f2bf(rA[rr].y);
            pk[2] = f2bf(rA[rr].z); pk[3] = f2bf(rA[rr].w);
            pk[4] = f2bf(rB[rr].x); pk[5] = f2bf(rB[rr].y);
            pk[6] = f2bf(rB[rr].z); pk[7] = f2bf(rB[rr].w);
            *(ushort8v*)&lA[lane >> 2][rl][((lane & 3) ^ ((rl >> 1) & 3)) * 8] = pk;
        }
        __syncthreads();

        // ---- GEMM: two 512-col chunks ----
#pragma unroll
        for (int ch = 0; ch < 2; ++ch) {
            f32x4 acc[4][4];
#pragma unroll
            for (int i = 0; i < 4; ++i)
#pragma unroll
                for (int j = 0; j < 4; ++j) acc[i][j] = (f32x4){0.f, 0.f, 0.f, 0.f};

            // stage kt=0 into buf 0
            {
                const unsigned short* src = cbbf_q +
                    ((size_t)ch * 512 + wave * 64 + (lane >> 2)) * DDIM + gch * 8;
                unsigned short* dst = &lB[0][wave * 64][0] + lane * 8;
#pragma unroll
                for (int t = 0; t < 4; ++t)
                    async_load16(src + (size_t)t * 16 * DDIM, dst + t * 16 * 32);
            }
#pragma unroll
            for (int kt = 0; kt < 16; ++kt) {
                if (kt < 15) {   // stage kt+1 into buf (kt+1)&1
                    const unsigned short* src = cbbf_q +
                        ((size_t)ch * 512 + wave * 64 + (lane >> 2)) * DDIM +
                        (size_t)(kt + 1) * 32 + gch * 8;
                    unsigned short* dst = &lB[(kt + 1) & 1][wave * 64][0] + lane * 8;
#pragma unroll
                    for (int t = 0; t < 4; ++t)
                        async_load16(src + (size_t)t * 16 * DDIM, dst + t * 16 * 32);
                }
                if (kt < 15) asm volatile("s_waitcnt vmcnt(4)" ::: "memory");
                else         asm volatile("s_waitcnt vmcnt(0)" ::: "memory");
                __builtin_amdgcn_s_barrier();
                __builtin_amdgcn_sched_barrier(0);

                short8 af[4], bfr[4];
#pragma unroll
                for (int i = 0; i < 4; ++i)
                    af[i] = *(const short8*)&lA[kt][i * 16 + l15][cq];
#pragma unroll
                for (int j = 0; j < 4; ++j)
                    bfr[j] = *(const short8*)&lB[kt & 1][wave * 64 + j * 16 + l15][cq];

                __builtin_amdgcn_s_setprio(1);
#pragma unroll
                for (int i = 0; i < 4; ++i)
#pragma unroll
                    for (int j = 0; j < 4; ++j)
                        acc[i][j] = __builtin_amdgcn_mfma_f32_16x16x32_bf16(
                            af[i], bfr[j], acc[i][j], 0, 0, 0);
                __builtin_amdgcn_s_setprio(0);
                __builtin_amdgcn_s_barrier();
            }

            // epilogue: row = i*16+quad*4+reg (local), col = ch*512+wave*64+j*16+l15
            const int colb = ch * 512 + wave * 64 + l15;
            const int g    = ch * 8 + wave;
            float cbs[4];
#pragma unroll
            for (int j = 0; j < 4; ++j) cbs[j] = cbsq_q[colb + j * 16];
#pragma unroll
            for (int i = 0; i < 4; ++i) {
#pragma unroll
                for (int reg = 0; reg < 4; ++reg) {
                    uint32_t k[4];
#pragma unroll
                    for (int j = 0; j < 4; ++j) {
                        float dv = cbs[j] - 2.0f * acc[i][j][reg];
                        k[j] = (fkey(dv) & ~1023u) | (uint32_t)(colb + j * 16);
                    }
                    uint32_t m01 = umin32(k[0], k[1]), M01 = umax32(k[0], k[1]);
                    uint32_t m23 = umin32(k[2], k[3]), M23 = umax32(k[2], k[3]);
                    uint32_t k1 = umin32(m01, m23);
                    uint32_t k2 = umin32(umax32(m01, m23), umin32(M01, M23));
#pragma unroll
                    for (int m = 1; m < 16; m <<= 1) {
                        uint32_t o1 = (uint32_t)__shfl_xor((int)k1, m, 64);
                        uint32_t o2 = (uint32_t)__shfl_xor((int)k2, m, 64);
                        uint32_t n1 = umin32(k1, o1);
                        uint32_t n2 = umin32(umax32(k1, o1), umin32(k2, o2));
                        k1 = n1; k2 = n2;
                    }
                    if (l15 == 0)
                        *(uint2*)&cand_lds[i * 16 + quad * 4 + reg][g * 2] =
                            make_uint2(k1, k2);
                }
            }
        }
        __syncthreads();   // cand_lds complete; all lA reads done

        // ---- refine: own 8 rows, two 4-row interleaved batches (R14 logic) ----
#pragma unroll
        for (int b2 = 0; b2 < 2; ++b2) {
            const int lr0 = wave * 8 + b2 * 4;
            uint32_t key[4], kmin[4];
            float sx[4];
#pragma unroll
            for (int i = 0; i < 4; ++i) {
                key[i] = 0xFFFFFFFFu;
                if (lane < 32) key[i] = cand_lds[lr0 + i][lane];
                kmin[i] = key[i];
            }
            for (int m = 32; m; m >>= 1) {
#pragma unroll
                for (int i = 0; i < 4; ++i)
                    kmin[i] = umin32(kmin[i], (uint32_t)__shfl_xor((int)kmin[i], m, 64));
            }
#pragma unroll
            for (int i = 0; i < 4; ++i) {
                const float4 a = rA[b2 * 4 + i], c = rB[b2 * 4 + i];
                sx[i] = a.x * a.x + a.y * a.y + a.z * a.z + a.w * a.w
                      + c.x * c.x + c.y * c.y + c.z * c.z + c.w * c.w;
            }
            for (int m = 32; m; m >>= 1) {
#pragma unroll
                for (int i = 0; i < 4; ++i) sx[i] += __shfl_xor(sx[i], m, 64);
            }
            unsigned long long mask[4];
#pragma unroll
            for (int i = 0; i < 4; ++i) {
                const float thr = funkey(kmin[i] & ~1023u) + MARGIN;
                mask[i] = __ballot(lane < 32 && funkey(key[i] & ~1023u) <= thr);
            }
            float best[4] = {1e30f, 1e30f, 1e30f, 1e30f};
            int bestc[4] = {CCODES, CCODES, CCODES, CCODES};
            while (mask[0] | mask[1] | mask[2] | mask[3]) {
                bool act[4]; int src[4], cc[4];
#pragma unroll
                for (int i = 0; i < 4; ++i) {
                    act[i] = (mask[i] != 0ull);
                    src[i] = act[i] ? (__ffsll(mask[i]) - 1) : 0;
                    if (act[i]) mask[i] &= mask[i] - 1;
                    cc[i] = __shfl((int)(key[i] & 1023u), src[i], 64);
                }
                float4 ca[4], cbb[4];
#pragma unroll
                for (int i = 0; i < 4; ++i) {
                    const float4* crow = (const float4*)(cb_q + (size_t)cc[i] * DDIM);
                    ca[i]  = crow[lane * 2];
                    cbb[i] = crow[lane * 2 + 1];
                }
                float d[4];
#pragma unroll
                for (int i = 0; i < 4; ++i) {
                    const float4 a = rA[b2 * 4 + i], c2 = rB[b2 * 4 + i];
                    d[i] = a.x * ca[i].x + a.y * ca[i].y + a.z * ca[i].z + a.w * ca[i].w
                         + c2.x * cbb[i].x + c2.y * cbb[i].y + c2.z * cbb[i].z + c2.w * cbb[i].w;
                }
                for (int m = 32; m; m >>= 1) {
#pragma unroll
                    for (int i = 0; i < 4; ++i) d[i] += __shfl_xor(d[i], m, 64);
                }
#pragma unroll
                for (int i = 0; i < 4; ++i) {
                    if (act[i]) {
                        const float de = (sx[i] - 2.0f * d[i]) + cbsq_q[cc[i]];
                        if (de < best[i] || (de == best[i] && cc[i] < bestc[i])) {
                            best[i] = de; bestc[i] = cc[i];
                        }
                    }
                }
            }
            // update registers + outputs
#pragma unroll
            for (int i = 0; i < 4; ++i) {
                const float4* cbest = (const float4*)(cb_q + (size_t)bestc[i] * DDIM);
                float4 ba = cbest[lane * 2], bb = cbest[lane * 2 + 1];
                rA[b2 * 4 + i].x -= ba.x; rA[b2 * 4 + i].y -= ba.y;
                rA[b2 * 4 + i].z -= ba.z; rA[b2 * 4 + i].w -= ba.w;
                rB[b2 * 4 + i].x -= bb.x; rB[b2 * 4 + i].y -= bb.y;
                rB[b2 * 4 + i].z -= bb.z; rB[b2 * 4 + i].w -= bb.w;
                if (lane == 0) {
                    const int nt = nt_base + lr0 + i;
                    out_idx[(size_t)nt * QSTAGE + q] = (float)bestc[i];
                    atomicAdd(&hist[q * CCODES + bestc[i]], 1u);
                    atomicAdd(&loss_bins[q * 256 + (nt & 255)], best[i]);
                }
            }
        }
        __syncthreads();   // refine done everywhere before lA rebuild next stage
    }

    // ---- write final residual back ----
#pragma unroll
    for (int rr = 0; rr < 8; ++rr) {
        float* rp = r + (size_t)(nt_base + wave * 8 + rr) * DDIM + lane * 8;
        *(float4*)rp = rA[rr];
        *(float4*)(rp + 4) = rB[rr];
    }
}

// --------------------------------------------------------------------------
// final: blocks [0,8192): out = x - r_final transposed back to (N,D,T);
//        block 8192: mean commit loss + mean perplexity
// grid 8193 x 256
// --------------------------------------------------------------------------
__global__ __launch_bounds__(256) void final_kernel(
    const float* __restrict__ x, const float* __restrict__ r,
    float* __restrict__ out,
    const unsigned int* __restrict__ hist, const float* __restrict__ loss_bins,
    float* __restrict__ out2)
{
    __shared__ float tile[32][33];    // [t'][d']
    __shared__ float red[4];
    __shared__ float perp_acc;
    const int tid = threadIdx.x, wave = tid >> 6, lane = tid & 63;

    if (blockIdx.x < 8192) {
        const int bidx = blockIdx.x;
        const int d0 = (bidx & 15) * 32;
        const int t0 = ((bidx >> 4) & 7) * 32;
        const int n  = bidx >> 7;
        const int tx = tid & 31, ty = tid >> 5;
#pragma unroll
        for (int s = 0; s < 4; ++s) {
            int tt = ty + s * 8;
            tile[tt][tx] = r[(size_t)(n * 256 + t0 + tt) * DDIM + d0 + tx];
        }
        __syncthreads();
        const float* xp = x + (size_t)n * (DDIM * 256);
        float* op = out + (size_t)n * (DDIM * 256);
#pragma unroll
        for (int s = 0; s < 4; ++s) {
            int dd = ty + s * 8;
            size_t off = (size_t)(d0 + dd) * 256 + t0 + tx;
            op[off] = xp[off] - tile[tx][dd];
        }
        return;
    }

    // scalars block
    if (tid == 0) perp_acc = 0.f;
    __syncthreads();
    for (int q = 0; q < QSTAGE; ++q) {
        float s = 0.f;
        for (int c = tid; c < CCODES; c += 256) {
            float p = (float)hist[q * CCODES + c] * (1.0f / (float)NTROWS);
            s += p * logf(p + 1e-10f);
        }
        s = wave_sum(s);
        if (lane == 0) red[wave] = s;
        __syncthreads();
        if (tid == 0) {
            float tot = red[0] + red[1] + red[2] + red[3];
            perp_acc += expf(-tot);
        }
        __syncthreads();
    }
    float ls = 0.f;
    for (int i = tid; i < QSTAGE * 256; i += 256) ls += loss_bins[i];
    ls = wave_sum(ls);
    if (lane == 0) red[wave] = ls;
    __syncthreads();
    if (tid == 0) {
        float lsum = red[0] + red[1] + red[2] + red[3];
        out2[0] = (lsum / (float)QSTAGE) / ((float)NTROWS * (float)DDIM);
        out2[1] = perp_acc / (float)QSTAGE;
    }
}

// --------------------------------------------------------------------------
extern "C" void kernel_launch(void* const* d_in, const int* in_sizes, int n_in,
                              void* d_out, int out_size, void* d_ws, size_t ws_size,
                              hipStream_t stream)
{
    const float* x  = (const float*)d_in[0];
    const float* cb = (const float*)d_in[1];
    float* out = (float*)d_out;
    char* ws = (char*)d_ws;

    float*          r      = (float*)(ws + OFF_R);
    unsigned short* cbbf   = (unsigned short*)(ws + OFF_CBBF);
    float*          cbsq   = (float*)(ws + OFF_CBSQ);
    unsigned int*   hist   = (unsigned int*)(ws + OFF_HIST);
    float*          lbins  = (float*)(ws + OFF_LOSS);

    prep_kernel<<<9728, 256, 0, stream>>>(x, cb, r, cbbf, cbsq, hist, lbins);

    fused_vq_kernel<<<256, 512, 0, stream>>>(
        r, cbbf, cb, cbsq, out + OUT_IDX_OFF, hist, lbins);

    final_kernel<<<8193, 256, 0, stream>>>(x, r, out, hist, lbins,
                                           out + OUT_SCAL_OFF);
}

// Round 12
// 406.245 us; speedup vs baseline: 1.3354x; 1.0487x over previous
//
#include <hip/hip_runtime.h>
#include <hip/hip_fp16.h>
#include <hip/hip_bf16.h>
#include <stdint.h>

// ---------------------------------------------------------------------------
// ResidualVQ: x (64,512,256) f32, codebooks (6,1024,512) f32
// outputs: quantized_out (64,512,256), indices (64,256,6) as f32,
//          mean_loss, mean_perplexity   -> d_out flat f32, 8486914 elems
//
// R16 -> R17: B-STAGING MADE CONTIGUOUS (one variable). R16 (426us, best)
// profile: fused = 334us, ~40us/stage in the gemm phase vs 7.4us L2-BW
// bound. Root cause: every async_load16 gathered 16 rows x 64B at 1KB
// stride (16 scattered transactions/instr) — the structural constant all
// null scheduling rounds (R6/R7/R8/R15) shared. Fix: prep writes cbbf in
// K-tiled PRE-SWIZZLED layout cbbf_t[q][kt][1024][32] (slot = chunk ^
// ((row>>1)&3) baked in), so fused staging is an identity copy of
// contiguous 1KB runs (src offset == dst offset == lane*16B). LDS image
// bit-identical to R16 -> ds_read/cq/MFMA/epilogue/refine untouched.
// ---------------------------------------------------------------------------

#define NTROWS 16384
#define DDIM   512
#define CCODES 1024
#define QSTAGE 6

// ws layout (bytes)
#define OFF_R      ((size_t)0)           // fp32 residual  NT*D*4   = 33554432
#define OFF_CBBF   ((size_t)50331648)    // bf16 codebooks (tiled) 6*16*1024*32*2
#define OFF_CBSQ   ((size_t)58720256)    // f32 |c|^2, 6*1024*4
#define OFF_HIST   ((size_t)58744832)    // u32 hist, 6*1024*4
#define OFF_LOSS   ((size_t)58769408)    // f32 loss bins, 6*256*4

#define OUT_IDX_OFF  ((size_t)8388608)
#define OUT_SCAL_OFF ((size_t)8486912)

typedef __attribute__((ext_vector_type(8))) short short8;
typedef __attribute__((ext_vector_type(8))) unsigned short ushort8v;
typedef __attribute__((ext_vector_type(4))) float f32x4;

__device__ __forceinline__ unsigned short f2bf(float f) {
    uint32_t u = __float_as_uint(f);
    uint32_t r = (u + 0x7fffu + ((u >> 16) & 1u)) >> 16;   // RNE
    return (unsigned short)r;
}
__device__ __forceinline__ uint32_t fkey(float f) {        // order-preserving f32->u32
    uint32_t u = __float_as_uint(f);
    return u ^ ((uint32_t)((int32_t)u >> 31) | 0x80000000u);
}
__device__ __forceinline__ float funkey(uint32_t k) {
    uint32_t u = (k & 0x80000000u) ? (k ^ 0x80000000u) : ~k;
    return __uint_as_float(u);
}
__device__ __forceinline__ uint32_t umin32(uint32_t a, uint32_t b) { return a < b ? a : b; }
__device__ __forceinline__ uint32_t umax32(uint32_t a, uint32_t b) { return a > b ? a : b; }
__device__ __forceinline__ float wave_sum(float v) {
    for (int m = 32; m; m >>= 1) v += __shfl_xor(v, m, 64);
    return v;
}
__device__ __forceinline__ void async_load16(const void* g, void* l) {
    __builtin_amdgcn_global_load_lds(
        (__attribute__((address_space(1))) void*)(void*)g,
        (__attribute__((address_space(3))) void*)l, 16, 0, 0);
}

// --------------------------------------------------------------------------
// prep: blocks [0,1536): bf16 codebooks -> TILED layout + |c|^2
//       blocks [1536,9728): transpose x (N,D,T) -> r (NT,D) fp32
// grid 9728 x 256
// Tiled layout: cbbf_t[q][kt][row][slot*8+j] = bf16(cb[q][row][kt*32 +
// (slot^((row>>1)&3))*8 + j]) — the staging swizzle baked in.
// --------------------------------------------------------------------------
__global__ __launch_bounds__(256) void prep_kernel(
    const float* __restrict__ x, const float* __restrict__ cb,
    float* __restrict__ r,
    unsigned short* __restrict__ cbbf, float* __restrict__ cbsq,
    unsigned int* __restrict__ hist, float* __restrict__ loss_bins)
{
    __shared__ float tile[32][33];
    if (blockIdx.x < 1536) {
        const int wave = threadIdx.x >> 6, lane = threadIdx.x & 63;
        const int row = blockIdx.x * 4 + wave;            // 0..6143
        const float* p = cb + (size_t)row * DDIM;
        const int grow = row & 1023;
        const int sr = (grow >> 1) & 3;
        unsigned short* tq = cbbf + (size_t)(row >> 10) * (16 * 1024 * 32);
        float s = 0.f;
#pragma unroll
        for (int t = 0; t < 8; ++t) {
            const int pidx = lane + 64 * t;
            float v = p[pidx];
            const int kt = pidx >> 5;
            const int slot = ((pidx >> 3) & 3) ^ sr;
            const int j = pidx & 7;
            tq[((size_t)(kt << 10) + grow) * 32 + slot * 8 + j] = f2bf(v);
            s += v * v;
        }
        s = wave_sum(s);
        if (lane == 0) cbsq[row] = s;
        if (blockIdx.x == 0) {
            for (int i = threadIdx.x; i < QSTAGE * CCODES; i += 256) hist[i] = 0u;
            for (int i = threadIdx.x; i < QSTAGE * 256; i += 256) loss_bins[i] = 0.f;
        }
    } else {
        const int bidx = blockIdx.x - 1536;               // 0..8191
        const int d0 = (bidx & 15) * 32;
        const int t0 = ((bidx >> 4) & 7) * 32;
        const int n  = bidx >> 7;
        const int tx = threadIdx.x & 31, ty = threadIdx.x >> 5;
        const float* xp = x + (size_t)n * (DDIM * 256);
#pragma unroll
        for (int s = 0; s < 4; ++s) {
            int dd = ty + s * 8;
            tile[dd][tx] = xp[(size_t)(d0 + dd) * 256 + t0 + tx];
        }
        __syncthreads();
#pragma unroll
        for (int s = 0; s < 4; ++s) {
            int tt = ty + s * 8;
            r[(size_t)(n * 256 + t0 + tt) * DDIM + d0 + tx] = tile[tx][tt];
        }
    }
}

// --------------------------------------------------------------------------
// FUSED: grid 256 x 512. Block b owns rows [b*64, b*64+64) in registers
// (wave w rows w*8..+8; lane l holds elems [l*8, l*8+8) as rA/rB float4).
// Per stage q: build lA bf16 -> GEMM 64x1024 in two 512-col chunks
// (db lB, counted vmcnt; B staged as contiguous identity copies from the
// tiled codebook) -> top-2 per 64-col group into cand_lds -> refine
// (R14 4-row interleave, register rows, fp32 cb) -> update regs.
// --------------------------------------------------------------------------
#define MARGIN 8.0f
__global__ __launch_bounds__(512, 2) void fused_vq_kernel(
    float* __restrict__ r,                     // NT x 512 fp32 (in/out)
    const unsigned short* __restrict__ cbbf,   // tiled 6*16*1024*32 bf16
    const float* __restrict__ cb,              // 6*1024*512 f32
    const float* __restrict__ cbsq,            // 6*1024
    float* __restrict__ out_idx, unsigned int* __restrict__ hist,
    float* __restrict__ loss_bins)
{
    __shared__ __align__(16) unsigned short lA[16][64][32];   // 64 KiB [kt][row][slot]
    __shared__ __align__(16) unsigned short lB[2][512][32];   // 64 KiB
    __shared__ uint32_t cand_lds[64][32];                     //  8 KiB

    const int tid = threadIdx.x;
    const int wave = tid >> 6, lane = tid & 63;
    const int quad = lane >> 4, l15 = lane & 15;
    const int nt_base = blockIdx.x * 64;

    // ---- load own 8 rows into registers ----
    float4 rA[8], rB[8];
#pragma unroll
    for (int rr = 0; rr < 8; ++rr) {
        const float* rp = r + (size_t)(nt_base + wave * 8 + rr) * DDIM + lane * 8;
        rA[rr] = *(const float4*)rp;
        rB[rr] = *(const float4*)(rp + 4);
    }

    const int cq = (quad ^ ((l15 >> 1) & 3)) * 8;    // swizzled read chunk

    for (int q = 0; q < QSTAGE; ++q) {
        const unsigned short* cbbf_q = cbbf + (size_t)q * (16 * 1024 * 32);
        const float* cb_q   = cb   + (size_t)q * CCODES * DDIM;
        const float* cbsq_q = cbsq + q * CCODES;

        // ---- build lA: row rl = wave*8+rr, lane l writes its 8 bf16
        // (elems l*8..+8) to [kt l>>2][row][slot (l&3)^((rl>>1)&3)] ----
#pragma unroll
        for (int rr = 0; rr < 8; ++rr) {
            const int rl = wave * 8 + rr;
            ushort8v pk;
            pk[0] = f2bf(rA[rr].x); pk[1] = f2bf(rA[rr].y);
            pk[2] = f2bf(rA[rr].z); pk[3] = f2bf(rA[rr].w);
            pk[4] = f2bf(rB[rr].x); pk[5] = f2bf(rB[rr].y);
            pk[6] = f2bf(rB[rr].z); pk[7] = f2bf(rB[rr].w);
            *(ushort8v*)&lA[lane >> 2][rl][((lane & 3) ^ ((rl >> 1) & 3)) * 8] = pk;
        }
        __syncthreads();

        // ---- GEMM: two 512-col chunks ----
#pragma unroll
        for (int ch = 0; ch < 2; ++ch) {
            f32x4 acc[4][4];
#pragma unroll
            for (int i = 0; i < 4; ++i)
#pragma unroll
                for (int j = 0; j < 4; ++j) acc[i][j] = (f32x4){0.f, 0.f, 0.f, 0.f};

            // stage kt=0 into buf 0 (identity copy of contiguous 1KB runs)
            {
                const unsigned short* src =
                    cbbf_q + ((size_t)ch * 512 + wave * 64) * 32 + lane * 8;
                unsigned short* dst = &lB[0][wave * 64][0] + lane * 8;
#pragma unroll
                for (int t = 0; t < 4; ++t)
                    async_load16(src + t * 512, dst + t * 512);
            }
#pragma unroll
            for (int kt = 0; kt < 16; ++kt) {
                if (kt < 15) {   // stage kt+1 into buf (kt+1)&1
                    const unsigned short* src = cbbf_q +
                        ((size_t)((kt + 1) << 10) + ch * 512 + wave * 64) * 32 +
                        lane * 8;
                    unsigned short* dst = &lB[(kt + 1) & 1][wave * 64][0] + lane * 8;
#pragma unroll
                    for (int t = 0; t < 4; ++t)
                        async_load16(src + t * 512, dst + t * 512);
                }
                if (kt < 15) asm volatile("s_waitcnt vmcnt(4)" ::: "memory");
                else         asm volatile("s_waitcnt vmcnt(0)" ::: "memory");
                __builtin_amdgcn_s_barrier();
                __builtin_amdgcn_sched_barrier(0);

                short8 af[4], bfr[4];
#pragma unroll
                for (int i = 0; i < 4; ++i)
                    af[i] = *(const short8*)&lA[kt][i * 16 + l15][cq];
#pragma unroll
                for (int j = 0; j < 4; ++j)
                    bfr[j] = *(const short8*)&lB[kt & 1][wave * 64 + j * 16 + l15][cq];

                __builtin_amdgcn_s_setprio(1);
#pragma unroll
                for (int i = 0; i < 4; ++i)
#pragma unroll
                    for (int j = 0; j < 4; ++j)
                        acc[i][j] = __builtin_amdgcn_mfma_f32_16x16x32_bf16(
                            af[i], bfr[j], acc[i][j], 0, 0, 0);
                __builtin_amdgcn_s_setprio(0);
                __builtin_amdgcn_s_barrier();
            }

            // epilogue: row = i*16+quad*4+reg (local), col = ch*512+wave*64+j*16+l15
            const int colb = ch * 512 + wave * 64 + l15;
            const int g    = ch * 8 + wave;
            float cbs[4];
#pragma unroll
            for (int j = 0; j < 4; ++j) cbs[j] = cbsq_q[colb + j * 16];
#pragma unroll
            for (int i = 0; i < 4; ++i) {
#pragma unroll
                for (int reg = 0; reg < 4; ++reg) {
                    uint32_t k[4];
#pragma unroll
                    for (int j = 0; j < 4; ++j) {
                        float dv = cbs[j] - 2.0f * acc[i][j][reg];
                        k[j] = (fkey(dv) & ~1023u) | (uint32_t)(colb + j * 16);
                    }
                    uint32_t m01 = umin32(k[0], k[1]), M01 = umax32(k[0], k[1]);
                    uint32_t m23 = umin32(k[2], k[3]), M23 = umax32(k[2], k[3]);
                    uint32_t k1 = umin32(m01, m23);
                    uint32_t k2 = umin32(umax32(m01, m23), umin32(M01, M23));
#pragma unroll
                    for (int m = 1; m < 16; m <<= 1) {
                        uint32_t o1 = (uint32_t)__shfl_xor((int)k1, m, 64);
                        uint32_t o2 = (uint32_t)__shfl_xor((int)k2, m, 64);
                        uint32_t n1 = umin32(k1, o1);
                        uint32_t n2 = umin32(umax32(k1, o1), umin32(k2, o2));
                        k1 = n1; k2 = n2;
                    }
                    if (l15 == 0)
                        *(uint2*)&cand_lds[i * 16 + quad * 4 + reg][g * 2] =
                            make_uint2(k1, k2);
                }
            }
        }
        __syncthreads();   // cand_lds complete; all lA reads done

        // ---- refine: own 8 rows, two 4-row interleaved batches (R14 logic) ----
#pragma unroll
        for (int b2 = 0; b2 < 2; ++b2) {
            const int lr0 = wave * 8 + b2 * 4;
            uint32_t key[4], kmin[4];
            float sx[4];
#pragma unroll
            for (int i = 0; i < 4; ++i) {
                key[i] = 0xFFFFFFFFu;
                if (lane < 32) key[i] = cand_lds[lr0 + i][lane];
                kmin[i] = key[i];
            }
            for (int m = 32; m; m >>= 1) {
#pragma unroll
                for (int i = 0; i < 4; ++i)
                    kmin[i] = umin32(kmin[i], (uint32_t)__shfl_xor((int)kmin[i], m, 64));
            }
#pragma unroll
            for (int i = 0; i < 4; ++i) {
                const float4 a = rA[b2 * 4 + i], c = rB[b2 * 4 + i];
                sx[i] = a.x * a.x + a.y * a.y + a.z * a.z + a.w * a.w
                      + c.x * c.x + c.y * c.y + c.z * c.z + c.w * c.w;
            }
            for (int m = 32; m; m >>= 1) {
#pragma unroll
                for (int i = 0; i < 4; ++i) sx[i] += __shfl_xor(sx[i], m, 64);
            }
            unsigned long long mask[4];
#pragma unroll
            for (int i = 0; i < 4; ++i) {
                const float thr = funkey(kmin[i] & ~1023u) + MARGIN;
                mask[i] = __ballot(lane < 32 && funkey(key[i] & ~1023u) <= thr);
            }
            float best[4] = {1e30f, 1e30f, 1e30f, 1e30f};
            int bestc[4] = {CCODES, CCODES, CCODES, CCODES};
            while (mask[0] | mask[1] | mask[2] | mask[3]) {
                bool act[4]; int src[4], cc[4];
#pragma unroll
                for (int i = 0; i < 4; ++i) {
                    act[i] = (mask[i] != 0ull);
                    src[i] = act[i] ? (__ffsll(mask[i]) - 1) : 0;
                    if (act[i]) mask[i] &= mask[i] - 1;
                    cc[i] = __shfl((int)(key[i] & 1023u), src[i], 64);
                }
                float4 ca[4], cbb[4];
#pragma unroll
                for (int i = 0; i < 4; ++i) {
                    const float4* crow = (const float4*)(cb_q + (size_t)cc[i] * DDIM);
                    ca[i]  = crow[lane * 2];
                    cbb[i] = crow[lane * 2 + 1];
                }
                float d[4];
#pragma unroll
                for (int i = 0; i < 4; ++i) {
                    const float4 a = rA[b2 * 4 + i], c2 = rB[b2 * 4 + i];
                    d[i] = a.x * ca[i].x + a.y * ca[i].y + a.z * ca[i].z + a.w * ca[i].w
                         + c2.x * cbb[i].x + c2.y * cbb[i].y + c2.z * cbb[i].z + c2.w * cbb[i].w;
                }
                for (int m = 32; m; m >>= 1) {
#pragma unroll
                    for (int i = 0; i < 4; ++i) d[i] += __shfl_xor(d[i], m, 64);
                }
#pragma unroll
                for (int i = 0; i < 4; ++i) {
                    if (act[i]) {
                        const float de = (sx[i] - 2.0f * d[i]) + cbsq_q[cc[i]];
                        if (de < best[i] || (de == best[i] && cc[i] < bestc[i])) {
                            best[i] = de; bestc[i] = cc[i];
                        }
                    }
                }
            }
            // update registers + outputs
#pragma unroll
            for (int i = 0; i < 4; ++i) {
                const float4* cbest = (const float4*)(cb_q + (size_t)bestc[i] * DDIM);
                float4 ba = cbest[lane * 2], bb = cbest[lane * 2 + 1];
                rA[b2 * 4 + i].x -= ba.x; rA[b2 * 4 + i].y -= ba.y;
                rA[b2 * 4 + i].z -= ba.z; rA[b2 * 4 + i].w -= ba.w;
                rB[b2 * 4 + i].x -= bb.x; rB[b2 * 4 + i].y -= bb.y;
                rB[b2 * 4 + i].z -= bb.z; rB[b2 * 4 + i].w -= bb.w;
                if (lane == 0) {
                    const int nt = nt_base + lr0 + i;
                    out_idx[(size_t)nt * QSTAGE + q] = (float)bestc[i];
                    atomicAdd(&hist[q * CCODES + bestc[i]], 1u);
                    atomicAdd(&loss_bins[q * 256 + (nt & 255)], best[i]);
                }
            }
        }
        __syncthreads();   // refine done everywhere before lA rebuild next stage
    }

    // ---- write final residual back ----
#pragma unroll
    for (int rr = 0; rr < 8; ++rr) {
        float* rp = r + (size_t)(nt_base + wave * 8 + rr) * DDIM + lane * 8;
        *(float4*)rp = rA[rr];
        *(float4*)(rp + 4) = rB[rr];
    }
}

// --------------------------------------------------------------------------
// final: blocks [0,8192): out = x - r_final transposed back to (N,D,T);
//        block 8192: mean commit loss + mean perplexity
// grid 8193 x 256
// --------------------------------------------------------------------------
__global__ __launch_bounds__(256) void final_kernel(
    const float* __restrict__ x, const float* __restrict__ r,
    float* __restrict__ out,
    const unsigned int* __restrict__ hist, const float* __restrict__ loss_bins,
    float* __restrict__ out2)
{
    __shared__ float tile[32][33];    // [t'][d']
    __shared__ float red[4];
    __shared__ float perp_acc;
    const int tid = threadIdx.x, wave = tid >> 6, lane = tid & 63;

    if (blockIdx.x < 8192) {
        const int bidx = blockIdx.x;
        const int d0 = (bidx & 15) * 32;
        const int t0 = ((bidx >> 4) & 7) * 32;
        const int n  = bidx >> 7;
        const int tx = tid & 31, ty = tid >> 5;
#pragma unroll
        for (int s = 0; s < 4; ++s) {
            int tt = ty + s * 8;
            tile[tt][tx] = r[(size_t)(n * 256 + t0 + tt) * DDIM + d0 + tx];
        }
        __syncthreads();
        const float* xp = x + (size_t)n * (DDIM * 256);
        float* op = out + (size_t)n * (DDIM * 256);
#pragma unroll
        for (int s = 0; s < 4; ++s) {
            int dd = ty + s * 8;
            size_t off = (size_t)(d0 + dd) * 256 + t0 + tx;
            op[off] = xp[off] - tile[tx][dd];
        }
        return;
    }

    // scalars block
    if (tid == 0) perp_acc = 0.f;
    __syncthreads();
    for (int q = 0; q < QSTAGE; ++q) {
        float s = 0.f;
        for (int c = tid; c < CCODES; c += 256) {
            float p = (float)hist[q * CCODES + c] * (1.0f / (float)NTROWS);
            s += p * logf(p + 1e-10f);
        }
        s = wave_sum(s);
        if (lane == 0) red[wave] = s;
        __syncthreads();
        if (tid == 0) {
            float tot = red[0] + red[1] + red[2] + red[3];
            perp_acc += expf(-tot);
        }
        __syncthreads();
    }
    float ls = 0.f;
    for (int i = tid; i < QSTAGE * 256; i += 256) ls += loss_bins[i];
    ls = wave_sum(ls);
    if (lane == 0) red[wave] = ls;
    __syncthreads();
    if (tid == 0) {
        float lsum = red[0] + red[1] + red[2] + red[3];
        out2[0] = (lsum / (float)QSTAGE) / ((float)NTROWS * (float)DDIM);
        out2[1] = perp_acc / (float)QSTAGE;
    }
}

// --------------------------------------------------------------------------
extern "C" void kernel_launch(void* const* d_in, const int* in_sizes, int n_in,
                              void* d_out, int out_size, void* d_ws, size_t ws_size,
                              hipStream_t stream)
{
    const float* x  = (const float*)d_in[0];
    const float* cb = (const float*)d_in[1];
    float* out = (float*)d_out;
    char* ws = (char*)d_ws;

    float*          r      = (float*)(ws + OFF_R);
    unsigned short* cbbf   = (unsigned short*)(ws + OFF_CBBF);
    float*          cbsq   = (float*)(ws + OFF_CBSQ);
    unsigned int*   hist   = (unsigned int*)(ws + OFF_HIST);
    float*          lbins  = (float*)(ws + OFF_LOSS);

    prep_kernel<<<9728, 256, 0, stream>>>(x, cb, r, cbbf, cbsq, hist, lbins);

    fused_vq_kernel<<<256, 512, 0, stream>>>(
        r, cbbf, cb, cbsq, out + OUT_IDX_OFF, hist, lbins);

    final_kernel<<<8193, 256, 0, stream>>>(x, r, out, hist, lbins,
                                           out + OUT_SCAL_OFF);
}